// Round 11
// baseline (99.113 us; speedup 1.0000x reference)
//
#include <hip/hip_runtime.h>
#include <hip/hip_bf16.h>
#include <math.h>

#define HW_   65536
#define B_    2
#define Q_    100
#define C_    134
#define T_    20
#define NHUN  100
#define MT_   7            // M-tiles of 16 queries (112 >= 100)
#define KSB   128          // K-split blocks per (b,mt)
#define BKCH  512          // k per block
#define PREC  1088         // part record stride (1024 frag + 16 F + 16 P + pad)

typedef __attribute__((ext_vector_type(8))) short bf16x8;
typedef __attribute__((ext_vector_type(4))) float f32x4;

// ws layout (float units)
#define LABPS_OFF  0                    // [2][20][8]
#define CC_OFF     512                  // [200][20] (fallback path only)
#define COST_OFF   4608                 // [200][20] (fallback path only)
#define BASE_END   8704
#define LABT_HI_F  BASE_END                         // 2*20*65536 ushort = 1,310,720 floats
#define PART_OFF   (LABT_HI_F + 1310720)            // 1792 records * 1088 floats
#define CSUM_OFF   (PART_OFF + B_ * KSB * MT_ * PREC)   // 14*1056
#define WS_END_F   (CSUM_OFF + B_ * MT_ * 1056)

__device__ inline unsigned short f2bf(float f) {
    unsigned int u = __builtin_bit_cast(unsigned int, f);
    u += 0x7FFFu + ((u >> 16) & 1u);               // RNE
    return (unsigned short)(u >> 16);
}
__device__ inline float softplusf(float x) {
    float ax = fabsf(x);
    return fmaxf(x, 0.0f) + log1pf(expf(-ax));
}

// ---------------- K1: decimate labels -> bf16 rows [b][t][65536] + row-sum partials ----------------
__global__ void lab_prep_kernel(const float* __restrict__ ml, unsigned short* __restrict__ labT,
                                float* __restrict__ lab_ps, int writeT) {
    int b = blockIdx.x, t = blockIdx.y, ksl = blockIdx.z;
    int tid = threadIdx.x;
    const float* src = ml + (size_t)(b * T_ + t) * 262144;
    size_t dst = ((size_t)(b * T_ + t)) << 16;
    float acc = 0.f;
    for (int it = 0; it < 8; ++it) {
        int k = ksl * 8192 + it * 1024 + tid * 4;
        int r = k >> 8, c = k & 255;
        const float* s = src + r * 1024 + 2 * c;
        float4 u = *(const float4*)s;
        float4 w = *(const float4*)(s + 4);
        float v[4] = {u.x, u.z, w.x, w.z};
        unsigned short h[4];
#pragma unroll
        for (int e = 0; e < 4; ++e) { h[e] = f2bf(v[e]); acc += v[e]; }
        if (writeT) *(ushort4*)(labT + dst + k) = make_ushort4(h[0], h[1], h[2], h[3]);
    }
    for (int off = 32; off > 0; off >>= 1) acc += __shfl_down(acc, off);
    __shared__ float sb[4];
    int wid = tid >> 6, lane = tid & 63;
    if (lane == 0) sb[wid] = acc;
    __syncthreads();
    if (tid == 0) lab_ps[(b * T_ + t) * 8 + ksl] = sb[0] + sb[1] + sb[2] + sb[3];
}

// ---------------- class cost (fallback path only) ----------------
__global__ void class_cost_kernel(const float* __restrict__ cl, const int* __restrict__ labels,
                                  float* __restrict__ cc) {
    int bq  = blockIdx.x;
    int b   = bq / Q_;
    int tid = threadIdx.x;         // 64
    __shared__ float sl[C_];
    const float* src = cl + (size_t)bq * C_;
    for (int c = tid; c < C_; c += 64) sl[c] = src[c];
    __syncthreads();
    float mx = -INFINITY;
    for (int c = tid; c < C_; c += 64) mx = fmaxf(mx, sl[c]);
    for (int off = 32; off > 0; off >>= 1) mx = fmaxf(mx, __shfl_xor(mx, off));
    float se = 0.f;
    for (int c = tid; c < C_; c += 64) se += expf(sl[c] - mx);
    for (int off = 32; off > 0; off >>= 1) se += __shfl_xor(se, off);
    float inv = 1.0f / se;
    if (tid < T_) {
        int lbl = labels[b * T_ + tid];
        cc[bq * T_ + tid] = -expf(sl[lbl] - mx) * inv;
    }
}

// ---------------- K3: fused pointwise + single-pass bf16 MFMA partials (R8-proven) ----------------
__global__ __launch_bounds__(256) void focal_mfma_kernel(
        const float* __restrict__ mq, const unsigned short* __restrict__ labT,
        float* __restrict__ part) {
    int idx = blockIdx.x;
    int mt  = idx % MT_;
    int rem = idx / MT_;
    int ks  = rem % KSB;
    int b   = rem / KSB;
    int tid  = threadIdx.x;
    int wave = tid >> 6, lane = tid & 63;
    int lg = lane >> 4, lr = lane & 15;

    int q = mt * 16 + lr;
    bool qok = (q < Q_);
    const float* xrow = mq + ((size_t)(b * Q_ + (qok ? q : 0)) << 16);
    int koff = ks * BKCH + wave * 128 + lg * 8;

    const unsigned short* b1 = labT + (((size_t)(b * T_ + lr)) << 16);
    const unsigned short* b2 = labT + (((size_t)(b * T_ + 16 + (lr & 3))) << 16);
    bool n2row = (lr < 4);

    f32x4 accD0 = {0,0,0,0}, accD1 = {0,0,0,0};
    f32x4 accP0 = {0,0,0,0}, accP1 = {0,0,0,0};
    float F = 0.f, P = 0.f;

    bf16x8 zer;
#pragma unroll
    for (int e = 0; e < 8; ++e) zer[e] = 0;

    for (int kk = 0; kk < 4; ++kk) {
        int kb = koff + kk * 32;
        float4 u0 = *(const float4*)(xrow + kb);
        float4 u1 = *(const float4*)(xrow + kb + 4);
        float xv[8] = {u0.x, u0.y, u0.z, u0.w, u1.x, u1.y, u1.z, u1.w};

        bf16x8 f1 = *(const bf16x8*)(b1 + kb);
        bf16x8 f2 = n2row ? *(const bf16x8*)(b2 + kb) : zer;

        bf16x8 dh, ph;
#pragma unroll
        for (int e = 0; e < 8; ++e) {
            float x  = xv[e];
            float ax = fabsf(x);
            float a  = __expf(-ax);
            float rr = 1.0f / (1.0f + a);
            float p  = (x >= 0.f) ? rr : a * rr;
            float om = (x >= 0.f) ? a * rr : rr;
            float l1 = __logf(1.0f + a);
            float spn = fmaxf(-x, 0.f) + l1;
            float spp = spn + x;
            float fp = 0.25f * om * om * spn;
            float fn = 0.75f * p * p * spp;
            F += fn; P += p;
            dh[e] = (short)f2bf(fp - fn);
            ph[e] = (short)f2bf(p);
        }
        accD0 = __builtin_amdgcn_mfma_f32_16x16x32_bf16(dh, f1, accD0, 0, 0, 0);
        accD1 = __builtin_amdgcn_mfma_f32_16x16x32_bf16(dh, f2, accD1, 0, 0, 0);
        accP0 = __builtin_amdgcn_mfma_f32_16x16x32_bf16(ph, f1, accP0, 0, 0, 0);
        accP1 = __builtin_amdgcn_mfma_f32_16x16x32_bf16(ph, f2, accP1, 0, 0, 0);
    }

    F += __shfl_down(F, 32); F += __shfl_down(F, 16);
    P += __shfl_down(P, 32); P += __shfl_down(P, 16);

    __shared__ float red[4][4][64][4];
    __shared__ float fpb[4][2][16];
#pragma unroll
    for (int r = 0; r < 4; ++r) {
        red[wave][0][lane][r] = accD0[r];
        red[wave][1][lane][r] = accD1[r];
        red[wave][2][lane][r] = accP0[r];
        red[wave][3][lane][r] = accP1[r];
    }
    if (lane < 16) { fpb[wave][0][lane] = F; fpb[wave][1][lane] = P; }
    __syncthreads();
    for (int e = tid; e < 1024; e += 256) {
        int f  = e >> 8;
        int l2 = (e & 255) >> 2;
        int r  = e & 3;
        part[(size_t)idx * PREC + e] =
            red[0][f][l2][r] + red[1][f][l2][r] + red[2][f][l2][r] + red[3][f][l2][r];
    }
    if (tid < 16)
        part[(size_t)idx * PREC + 1024 + tid] =
            fpb[0][0][tid] + fpb[1][0][tid] + fpb[2][0][tid] + fpb[3][0][tid];
    else if (tid < 32) {
        int l = tid - 16;
        part[(size_t)idx * PREC + 1040 + l] =
            fpb[0][1][l] + fpb[1][1][l] + fpb[2][1][l] + fpb[3][1][l];
    }
}

// ---------------- K4a: parallel K-split reduction: part -> Csum[14][1056] ----------------
__global__ __launch_bounds__(256) void reduce_part_kernel(const float* __restrict__ part,
                                                          float* __restrict__ Csum) {
    int bm   = blockIdx.x;          // 0..13
    int mt   = bm % MT_;
    int b    = bm / MT_;
    int tid  = threadIdx.x;
    int epos = tid & 31;
    int grp  = tid >> 5;            // 0..7
    int e    = blockIdx.y * 32 + epos;   // 0..1055

    const float* base = part + (size_t)((b * KSB) * MT_ + mt) * PREC + e;
    float s = 0.f;
    for (int k = 0; k < 16; ++k) {
        s += base[(size_t)(grp * 16 + k) * MT_ * PREC];
    }
    __shared__ float red[8][33];
    red[grp][epos] = s;
    __syncthreads();
    if (tid < 32) {
        float tot = 0.f;
        for (int g = 0; g < 8; ++g) tot += red[g][tid];
        Csum[(size_t)bm * 1056 + e] = tot;
    }
}

// ---------------- fallback: monolithic (round-2 proven) ----------------
__global__ __launch_bounds__(1024) void mask_cost_mono_kernel(
        const float* __restrict__ mq, const float* __restrict__ ml,
        const float* __restrict__ cc, const float* __restrict__ lab_ps,
        float* __restrict__ cost) {
    int bq  = blockIdx.x;
    int b   = bq / Q_;
    int tid = threadIdx.x;
    const float* xb  = mq + (size_t)bq * HW_;
    const float* mlb = ml + (size_t)b * T_ * 262144;
    float s1[T_], s2[T_];
#pragma unroll
    for (int t = 0; t < T_; ++t) { s1[t] = 0.f; s2[t] = 0.f; }
    float F = 0.f, P = 0.f;
    for (int k = tid; k < HW_; k += 1024) {
        int i = k >> 8, j = k & 255;
        float x = xb[k];
        float p = 1.0f / (1.0f + expf(-x));
        float spn = softplusf(-x);
        float spp = softplusf(x);
        float om = 1.0f - p;
        float fp = 0.25f * om * om * spn;
        float fn = 0.75f * p * p * spp;
        F += fn; P += p;
        float diff = fp - fn;
        int off0 = i * 1024 + 2 * j;
#pragma unroll
        for (int t = 0; t < T_; ++t) {
            float lab = mlb[t * 262144 + off0];
            s1[t] = fmaf(diff, lab, s1[t]);
            s2[t] = fmaf(p,    lab, s2[t]);
        }
    }
    __shared__ float sbuf[16][42];
    int wid = tid >> 6, lane = tid & 63;
#pragma unroll
    for (int t = 0; t < T_; ++t) {
        for (int off = 32; off > 0; off >>= 1) {
            s1[t] += __shfl_down(s1[t], off);
            s2[t] += __shfl_down(s2[t], off);
        }
    }
    for (int off = 32; off > 0; off >>= 1) { F += __shfl_down(F, off); P += __shfl_down(P, off); }
    if (lane == 0) {
#pragma unroll
        for (int t = 0; t < T_; ++t) { sbuf[wid][t] = s1[t]; sbuf[wid][T_ + t] = s2[t]; }
        sbuf[wid][40] = F; sbuf[wid][41] = P;
    }
    __syncthreads();
    if (tid < T_) {
        float S1 = 0.f, S2 = 0.f, Fs = 0.f, Ps = 0.f;
        for (int w = 0; w < 16; ++w) {
            S1 += sbuf[w][tid]; S2 += sbuf[w][T_ + tid];
            Fs += sbuf[w][40];  Ps += sbuf[w][41];
        }
        float L = 0.f;
        for (int sl = 0; sl < 8; ++sl) L += lab_ps[(b * T_ + tid) * 8 + sl];
        float cm = (S1 + Fs) * (1.0f / (float)HW_);
        float cd = 1.0f - (2.0f * S2 + 1.0f) / (Ps + L + 1.0f);
        cost[bq * T_ + tid] = cm + cd + cc[bq * T_ + tid];
    }
}

// ---------------- K5: fused compose + transposed rectangular JV Hungarian ----------------
// grid B_, 256 thr. fused=1: build cost in LDS from Csum + class-softmax (R8-compose math,
// identical op order). fused=0 (fallback): read cost[] from global. Wave 0 then runs the
// proven single-wave JV; all 4 waves keep a uniform 2-barriers-per-phase structure.
__global__ __launch_bounds__(256) void hungarian_kernel(
        const float* __restrict__ Csum, const float* __restrict__ cl,
        const int* __restrict__ labels_g, const float* __restrict__ lab_ps,
        const float* __restrict__ cost_g, int* __restrict__ out, int fused) {
    int b    = blockIdx.x;
    int tid  = threadIdx.x;
    int wave = tid >> 6, lane = tid & 63;

    __shared__ float csh[Q_ * T_];
    __shared__ float u[T_ + 1];
    __shared__ int   p[NHUN + 1];
    __shared__ int   way[NHUN + 1];
    __shared__ int   lbl[T_];
    __shared__ float Lt[T_];

    if (fused) {
        if (tid < T_) {
            lbl[tid] = labels_g[b * T_ + tid];
            float L = 0.f;
            for (int s8 = 0; s8 < 8; ++s8) L += lab_ps[(b * T_ + tid) * 8 + s8];
            Lt[tid] = L;
        }
        __syncthreads();
        if (tid < Q_) {
            int q  = tid;
            int mt = q >> 4, qm = q & 15;
            const float* C   = Csum + (size_t)(b * MT_ + mt) * 1056;
            const float* row = cl + (size_t)(b * Q_ + q) * C_;
            float m = -INFINITY;
            for (int c = 0; c < C_; ++c) m = fmaxf(m, row[c]);
            float s = 0.f;
            for (int c = 0; c < C_; ++c) s += expf(row[c] - m);
            float F = C[1024 + qm];
            float P = C[1040 + qm];
#pragma unroll
            for (int t = 0; t < T_; ++t) {
                int nt = t >> 4;
                int ln = ((qm >> 2) << 4) | (t & 15);
                int rg = qm & 3;
                float Sd = C[(0 + nt) * 256 + ln * 4 + rg];
                float Sp = C[(2 + nt) * 256 + ln * 4 + rg];
                float ccv = -expf(row[lbl[t]] - m) / s;
                float cm = (Sd + F) * (1.0f / (float)HW_);
                float cd = 1.0f - (2.0f * Sp + 1.0f) / (P + Lt[t] + 1.0f);
                csh[q * T_ + t] = cm + cd + ccv;
            }
        }
    } else {
        for (int idx = tid; idx < Q_ * T_; idx += 256)
            csh[idx] = cost_g[b * Q_ * T_ + idx];
    }
    for (int j = tid; j <= NHUN; j += 256) { p[j] = 0; way[j] = 0; }
    if (tid <= T_) u[tid] = 0.f;
    __syncthreads();

    const int ja = lane;            // column A (0 = virtual root on lane 0)
    const int jb = lane + 64;       // column B (valid up to 100)
    const bool jb_ok = (jb <= NHUN);
    float v_a = 0.f, v_b = 0.f;

    for (int i = 1; i <= T_; ++i) {
        if (tid == 0) p[0] = i;
        __syncthreads();
        if (wave == 0) {
            float m_a = INFINITY, m_b = INFINITY;
            bool us_a = false, us_b = false;
            int j0 = 0;
            while (true) {
                if (ja == j0) us_a = true;
                if (jb == j0) us_b = true;
                int   i0  = p[j0];
                float ui0 = u[i0];
                bool fa = (!us_a && ja >= 1);
                bool fb = (jb_ok && !us_b);
                if (fa) {
                    float cur = csh[(ja - 1) * T_ + (i0 - 1)] - ui0 - v_a;
                    if (cur < m_a) { m_a = cur; way[ja] = j0; }
                }
                if (fb) {
                    float cur = csh[(jb - 1) * T_ + (i0 - 1)] - ui0 - v_b;
                    if (cur < m_b) { m_b = cur; way[jb] = j0; }
                }
                float ca = fa ? m_a : INFINITY;
                float cb = fb ? m_b : INFINITY;
                float vmin = fminf(ca, cb);
                for (int off = 32; off > 0; off >>= 1)
                    vmin = fminf(vmin, __shfl_xor(vmin, off));
                unsigned long long ba = __ballot(ca == vmin);
                int j1;
                if (ba) j1 = __ffsll(ba) - 1;
                else    j1 = __ffsll(__ballot(cb == vmin)) - 1 + 64;
                float delta = vmin;
                if (us_a) { u[p[ja]] += delta; v_a -= delta; } else { m_a -= delta; }
                if (jb_ok) {
                    if (us_b) { u[p[jb]] += delta; v_b -= delta; } else { m_b -= delta; }
                }
                __threadfence_block();
                j0 = j1;
                if (p[j0] == 0) break;
            }
            if (lane == 0) {
                int jj = j0;
                while (jj) { int jn = way[jj]; p[jj] = p[jn]; jj = jn; }
            }
        }
        __syncthreads();
    }

    if (tid == 0) {
        int* ob = out + b * 2 * T_;
        int k = 0;
        for (int j = 1; j <= NHUN; ++j) {
            if (p[j] != 0) { ob[k] = j - 1; ob[T_ + k] = p[j] - 1; ++k; }
        }
    }
}

extern "C" void kernel_launch(void* const* d_in, const int* in_sizes, int n_in,
                              void* d_out, int out_size, void* d_ws, size_t ws_size,
                              hipStream_t stream) {
    const float* mq     = (const float*)d_in[0];   // [2,100,256,256]
    const float* cl     = (const float*)d_in[1];   // [2,100,134]
    const float* ml     = (const float*)d_in[2];   // [2,20,512,512]
    const int*   labels = (const int*)d_in[3];     // [2,20]
    int* out = (int*)d_out;                        // [2,2,20] int32
    float* ws = (float*)d_ws;

    float* lab_ps = ws + LABPS_OFF;
    float* cc     = ws + CC_OFF;
    float* cost   = ws + COST_OFF;

    size_t need = (size_t)WS_END_F * 4;

    if (ws_size >= need) {
        unsigned short* labT = (unsigned short*)(ws + LABT_HI_F);
        float* part = ws + PART_OFF;
        float* Csum = ws + CSUM_OFF;
        hipLaunchKernelGGL(lab_prep_kernel,   dim3(B_, T_, 8), dim3(256), 0, stream,
                           ml, labT, lab_ps, 1);
        hipLaunchKernelGGL(focal_mfma_kernel, dim3(B_ * KSB * MT_), dim3(256), 0, stream,
                           mq, labT, part);
        hipLaunchKernelGGL(reduce_part_kernel, dim3(B_ * MT_, 33), dim3(256), 0, stream,
                           part, Csum);
        hipLaunchKernelGGL(hungarian_kernel,  dim3(B_), dim3(256), 0, stream,
                           Csum, cl, labels, lab_ps, cost, out, 1);
    } else {
        hipLaunchKernelGGL(lab_prep_kernel,   dim3(B_, T_, 8), dim3(256), 0, stream,
                           ml, (unsigned short*)ws, lab_ps, 0);
        hipLaunchKernelGGL(class_cost_kernel, dim3(B_ * Q_),   dim3(64),  0, stream, cl, labels, cc);
        hipLaunchKernelGGL(mask_cost_mono_kernel, dim3(B_ * Q_), dim3(1024), 0, stream,
                           mq, ml, cc, lab_ps, cost);
        hipLaunchKernelGGL(hungarian_kernel,  dim3(B_), dim3(256), 0, stream,
                           ws, cl, labels, lab_ps, cost, out, 0);
    }
}

// Round 12
// 70.887 us; speedup vs baseline: 1.3982x; 1.3982x over previous
//
#include <hip/hip_runtime.h>
#include <hip/hip_bf16.h>
#include <math.h>

#define HW_   65536
#define B_    2
#define Q_    100
#define C_    134
#define T_    20
#define NHUN  100
#define MT_   7            // M-tiles of 16 queries (112 >= 100)
#define KSB   128          // K-split blocks per (b,mt)
#define BKCH  512          // k per block
#define PREC  1088         // part record stride (1024 frag + 16 F + 16 P + pad)
#define CPAD  21           // padded cost row stride (floats) in hungarian LDS

typedef __attribute__((ext_vector_type(8))) short bf16x8;
typedef __attribute__((ext_vector_type(4))) float f32x4;

// ws layout (float units)
#define LABPS_OFF  0                    // [2][20][8]
#define CC_OFF     512                  // [200][20] (fallback path only)
#define COST_OFF   4608                 // [200][20]
#define BASE_END   8704
#define LABT_HI_F  BASE_END                         // 2*20*65536 ushort = 1,310,720 floats
#define PART_OFF   (LABT_HI_F + 1310720)            // 1792 records * 1088 floats
#define CSUM_OFF   (PART_OFF + B_ * KSB * MT_ * PREC)   // 14*1056
#define WS_END_F   (CSUM_OFF + B_ * MT_ * 1056)

__device__ inline unsigned short f2bf(float f) {
    unsigned int u = __builtin_bit_cast(unsigned int, f);
    u += 0x7FFFu + ((u >> 16) & 1u);               // RNE
    return (unsigned short)(u >> 16);
}
__device__ inline float softplusf(float x) {
    float ax = fabsf(x);
    return fmaxf(x, 0.0f) + log1pf(expf(-ax));
}

// ---------------- K1: decimate labels -> bf16 rows [b][t][65536] + row-sum partials ----------------
__global__ void lab_prep_kernel(const float* __restrict__ ml, unsigned short* __restrict__ labT,
                                float* __restrict__ lab_ps, int writeT) {
    int b = blockIdx.x, t = blockIdx.y, ksl = blockIdx.z;
    int tid = threadIdx.x;
    const float* src = ml + (size_t)(b * T_ + t) * 262144;
    size_t dst = ((size_t)(b * T_ + t)) << 16;
    float acc = 0.f;
    for (int it = 0; it < 8; ++it) {
        int k = ksl * 8192 + it * 1024 + tid * 4;
        int r = k >> 8, c = k & 255;
        const float* s = src + r * 1024 + 2 * c;
        float4 u = *(const float4*)s;
        float4 w = *(const float4*)(s + 4);
        float v[4] = {u.x, u.z, w.x, w.z};
        unsigned short h[4];
#pragma unroll
        for (int e = 0; e < 4; ++e) { h[e] = f2bf(v[e]); acc += v[e]; }
        if (writeT) *(ushort4*)(labT + dst + k) = make_ushort4(h[0], h[1], h[2], h[3]);
    }
    for (int off = 32; off > 0; off >>= 1) acc += __shfl_down(acc, off);
    __shared__ float sb[4];
    int wid = tid >> 6, lane = tid & 63;
    if (lane == 0) sb[wid] = acc;
    __syncthreads();
    if (tid == 0) lab_ps[(b * T_ + t) * 8 + ksl] = sb[0] + sb[1] + sb[2] + sb[3];
}

// ---------------- class cost (fallback path only) ----------------
__global__ void class_cost_kernel(const float* __restrict__ cl, const int* __restrict__ labels,
                                  float* __restrict__ cc) {
    int bq  = blockIdx.x;
    int b   = bq / Q_;
    int tid = threadIdx.x;         // 64
    __shared__ float sl[C_];
    const float* src = cl + (size_t)bq * C_;
    for (int c = tid; c < C_; c += 64) sl[c] = src[c];
    __syncthreads();
    float mx = -INFINITY;
    for (int c = tid; c < C_; c += 64) mx = fmaxf(mx, sl[c]);
    for (int off = 32; off > 0; off >>= 1) mx = fmaxf(mx, __shfl_xor(mx, off));
    float se = 0.f;
    for (int c = tid; c < C_; c += 64) se += expf(sl[c] - mx);
    for (int off = 32; off > 0; off >>= 1) se += __shfl_xor(se, off);
    float inv = 1.0f / se;
    if (tid < T_) {
        int lbl = labels[b * T_ + tid];
        cc[bq * T_ + tid] = -expf(sl[lbl] - mx) * inv;
    }
}

// ---------------- K3: fused pointwise + single-pass bf16 MFMA partials (R8-proven) ----------------
__global__ __launch_bounds__(256) void focal_mfma_kernel(
        const float* __restrict__ mq, const unsigned short* __restrict__ labT,
        float* __restrict__ part) {
    int idx = blockIdx.x;
    int mt  = idx % MT_;
    int rem = idx / MT_;
    int ks  = rem % KSB;
    int b   = rem / KSB;
    int tid  = threadIdx.x;
    int wave = tid >> 6, lane = tid & 63;
    int lg = lane >> 4, lr = lane & 15;

    int q = mt * 16 + lr;
    bool qok = (q < Q_);
    const float* xrow = mq + ((size_t)(b * Q_ + (qok ? q : 0)) << 16);
    int koff = ks * BKCH + wave * 128 + lg * 8;

    const unsigned short* b1 = labT + (((size_t)(b * T_ + lr)) << 16);
    const unsigned short* b2 = labT + (((size_t)(b * T_ + 16 + (lr & 3))) << 16);
    bool n2row = (lr < 4);

    f32x4 accD0 = {0,0,0,0}, accD1 = {0,0,0,0};
    f32x4 accP0 = {0,0,0,0}, accP1 = {0,0,0,0};
    float F = 0.f, P = 0.f;

    bf16x8 zer;
#pragma unroll
    for (int e = 0; e < 8; ++e) zer[e] = 0;

    for (int kk = 0; kk < 4; ++kk) {
        int kb = koff + kk * 32;
        float4 u0 = *(const float4*)(xrow + kb);
        float4 u1 = *(const float4*)(xrow + kb + 4);
        float xv[8] = {u0.x, u0.y, u0.z, u0.w, u1.x, u1.y, u1.z, u1.w};

        bf16x8 f1 = *(const bf16x8*)(b1 + kb);
        bf16x8 f2 = n2row ? *(const bf16x8*)(b2 + kb) : zer;

        bf16x8 dh, ph;
#pragma unroll
        for (int e = 0; e < 8; ++e) {
            float x  = xv[e];
            float ax = fabsf(x);
            float a  = __expf(-ax);
            float rr = 1.0f / (1.0f + a);
            float p  = (x >= 0.f) ? rr : a * rr;
            float om = (x >= 0.f) ? a * rr : rr;
            float l1 = __logf(1.0f + a);
            float spn = fmaxf(-x, 0.f) + l1;
            float spp = spn + x;
            float fp = 0.25f * om * om * spn;
            float fn = 0.75f * p * p * spp;
            F += fn; P += p;
            dh[e] = (short)f2bf(fp - fn);
            ph[e] = (short)f2bf(p);
        }
        accD0 = __builtin_amdgcn_mfma_f32_16x16x32_bf16(dh, f1, accD0, 0, 0, 0);
        accD1 = __builtin_amdgcn_mfma_f32_16x16x32_bf16(dh, f2, accD1, 0, 0, 0);
        accP0 = __builtin_amdgcn_mfma_f32_16x16x32_bf16(ph, f1, accP0, 0, 0, 0);
        accP1 = __builtin_amdgcn_mfma_f32_16x16x32_bf16(ph, f2, accP1, 0, 0, 0);
    }

    F += __shfl_down(F, 32); F += __shfl_down(F, 16);
    P += __shfl_down(P, 32); P += __shfl_down(P, 16);

    __shared__ float red[4][4][64][4];
    __shared__ float fpb[4][2][16];
#pragma unroll
    for (int r = 0; r < 4; ++r) {
        red[wave][0][lane][r] = accD0[r];
        red[wave][1][lane][r] = accD1[r];
        red[wave][2][lane][r] = accP0[r];
        red[wave][3][lane][r] = accP1[r];
    }
    if (lane < 16) { fpb[wave][0][lane] = F; fpb[wave][1][lane] = P; }
    __syncthreads();
    for (int e = tid; e < 1024; e += 256) {
        int f  = e >> 8;
        int l2 = (e & 255) >> 2;
        int r  = e & 3;
        part[(size_t)idx * PREC + e] =
            red[0][f][l2][r] + red[1][f][l2][r] + red[2][f][l2][r] + red[3][f][l2][r];
    }
    if (tid < 16)
        part[(size_t)idx * PREC + 1024 + tid] =
            fpb[0][0][tid] + fpb[1][0][tid] + fpb[2][0][tid] + fpb[3][0][tid];
    else if (tid < 32) {
        int l = tid - 16;
        part[(size_t)idx * PREC + 1040 + l] =
            fpb[0][1][l] + fpb[1][1][l] + fpb[2][1][l] + fpb[3][1][l];
    }
}

// ---------------- K4a: parallel K-split reduction: part -> Csum[14][1056] ----------------
__global__ __launch_bounds__(256) void reduce_part_kernel(const float* __restrict__ part,
                                                          float* __restrict__ Csum) {
    int bm   = blockIdx.x;          // 0..13
    int mt   = bm % MT_;
    int b    = bm / MT_;
    int tid  = threadIdx.x;
    int epos = tid & 31;
    int grp  = tid >> 5;            // 0..7
    int e    = blockIdx.y * 32 + epos;   // 0..1055

    const float* base = part + (size_t)((b * KSB) * MT_ + mt) * PREC + e;
    float s = 0.f;
    for (int k = 0; k < 16; ++k) {
        s += base[(size_t)(grp * 16 + k) * MT_ * PREC];
    }
    __shared__ float red[8][33];
    red[grp][epos] = s;
    __syncthreads();
    if (tid < 32) {
        float tot = 0.f;
        for (int g = 0; g < 8; ++g) tot += red[g][tid];
        Csum[(size_t)bm * 1056 + e] = tot;
    }
}

// ---------------- K4b: finalize cost from Csum + fused class-softmax (R8-proven) ----------------
__global__ __launch_bounds__(320) void compose_kernel(
        const float* __restrict__ Csum, const float* __restrict__ cl,
        const int* __restrict__ labels, const float* __restrict__ lab_ps,
        float* __restrict__ cost) {
    int bm = blockIdx.x;
    int mt = bm % MT_;
    int b  = bm / MT_;
    int tid = threadIdx.x;     // 320
    int q0 = mt * 16;

    __shared__ float sl[16][136];
    __shared__ float mx[16], se[16];
    __shared__ int   lbl[T_];
    for (int e = tid; e < 16 * C_; e += 320) {
        int qm = e / C_, c = e % C_;
        int q = q0 + qm;
        sl[qm][c] = (q < Q_) ? cl[(size_t)(b * Q_ + q) * C_ + c] : 0.f;
    }
    if (tid < T_) lbl[tid] = labels[b * T_ + tid];
    __syncthreads();
    if (tid < 16) {
        float m = -INFINITY;
        for (int c = 0; c < C_; ++c) m = fmaxf(m, sl[tid][c]);
        float s = 0.f;
        for (int c = 0; c < C_; ++c) s += expf(sl[tid][c] - m);
        mx[tid] = m; se[tid] = s;
    }
    __syncthreads();

    int qm = tid / T_, t = tid % T_;
    int q = q0 + qm;
    if (qm < 16 && q < Q_) {
        const float* C = Csum + (size_t)bm * 1056;
        int nt   = t >> 4;
        int lane = ((qm >> 2) << 4) | (t & 15);
        int reg  = qm & 3;
        float Sd = C[(0 + nt) * 256 + lane * 4 + reg];
        float Sp = C[(2 + nt) * 256 + lane * 4 + reg];
        float F  = C[1024 + qm];
        float P  = C[1040 + qm];
        float L = 0.f;
        for (int s8 = 0; s8 < 8; ++s8) L += lab_ps[(b * T_ + t) * 8 + s8];
        float ccv = -expf(sl[qm][lbl[t]] - mx[qm]) / se[qm];
        float cm = (Sd + F) * (1.0f / (float)HW_);
        float cd = 1.0f - (2.0f * Sp + 1.0f) / (P + L + 1.0f);
        cost[(size_t)(b * Q_ + q) * T_ + t] = cm + cd + ccv;
    }
}

// ---------------- fallback: monolithic (round-2 proven) ----------------
__global__ __launch_bounds__(1024) void mask_cost_mono_kernel(
        const float* __restrict__ mq, const float* __restrict__ ml,
        const float* __restrict__ cc, const float* __restrict__ lab_ps,
        float* __restrict__ cost) {
    int bq  = blockIdx.x;
    int b   = bq / Q_;
    int tid = threadIdx.x;
    const float* xb  = mq + (size_t)bq * HW_;
    const float* mlb = ml + (size_t)b * T_ * 262144;
    float s1[T_], s2[T_];
#pragma unroll
    for (int t = 0; t < T_; ++t) { s1[t] = 0.f; s2[t] = 0.f; }
    float F = 0.f, P = 0.f;
    for (int k = tid; k < HW_; k += 1024) {
        int i = k >> 8, j = k & 255;
        float x = xb[k];
        float p = 1.0f / (1.0f + expf(-x));
        float spn = softplusf(-x);
        float spp = softplusf(x);
        float om = 1.0f - p;
        float fp = 0.25f * om * om * spn;
        float fn = 0.75f * p * p * spp;
        F += fn; P += p;
        float diff = fp - fn;
        int off0 = i * 1024 + 2 * j;
#pragma unroll
        for (int t = 0; t < T_; ++t) {
            float lab = mlb[t * 262144 + off0];
            s1[t] = fmaf(diff, lab, s1[t]);
            s2[t] = fmaf(p,    lab, s2[t]);
        }
    }
    __shared__ float sbuf[16][42];
    int wid = tid >> 6, lane = tid & 63;
#pragma unroll
    for (int t = 0; t < T_; ++t) {
        for (int off = 32; off > 0; off >>= 1) {
            s1[t] += __shfl_down(s1[t], off);
            s2[t] += __shfl_down(s2[t], off);
        }
    }
    for (int off = 32; off > 0; off >>= 1) { F += __shfl_down(F, off); P += __shfl_down(P, off); }
    if (lane == 0) {
#pragma unroll
        for (int t = 0; t < T_; ++t) { sbuf[wid][t] = s1[t]; sbuf[wid][T_ + t] = s2[t]; }
        sbuf[wid][40] = F; sbuf[wid][41] = P;
    }
    __syncthreads();
    if (tid < T_) {
        float S1 = 0.f, S2 = 0.f, Fs = 0.f, Ps = 0.f;
        for (int w = 0; w < 16; ++w) {
            S1 += sbuf[w][tid]; S2 += sbuf[w][T_ + tid];
            Fs += sbuf[w][40];  Ps += sbuf[w][41];
        }
        float L = 0.f;
        for (int sl = 0; sl < 8; ++sl) L += lab_ps[(b * T_ + tid) * 8 + sl];
        float cm = (S1 + Fs) * (1.0f / (float)HW_);
        float cd = 1.0f - (2.0f * S2 + 1.0f) / (Ps + L + 1.0f);
        cost[bq * T_ + tid] = cm + cd + cc[bq * T_ + tid];
    }
}

// ---------------- K5: register-resident JV Hungarian with greedy row-reduction init ----------------
// One wave per batch. Exact: feasible dual (u=row-min, v=0) + tight greedy matching +
// shortest-augmenting-path phases for the leftover rows => unique rectangular optimum
// (same assignment as the reference's padded square solve). Tie-breaks: lowest column
// index via ballot/ffsll (ja cols 1..63 all precede jb cols 64..100).
__global__ __launch_bounds__(64) void hungarian_kernel(const float* __restrict__ cost,
                                                       int* __restrict__ out) {
    int b    = blockIdx.x;
    int lane = threadIdx.x;

    __shared__ float csh[Q_ * CPAD];     // padded rows: col j-1 -> csh[(j-1)*CPAD + (i-1)]
    __shared__ int   psh[NHUN + 1];

    for (int j = lane; j < Q_; j += 64) {
#pragma unroll
        for (int t = 0; t < T_; ++t)
            csh[j * CPAD + t] = cost[b * Q_ * T_ + j * T_ + t];
    }
    __syncthreads();

    const int ja = lane;                 // 0 = virtual root (not a real column)
    const int jb = lane + 64;            // 64..100 valid iff <= NHUN
    const bool ja_ok = (ja >= 1);
    const bool jb_ok = (jb <= NHUN);

    int   p_a = 0, p_b = 0;              // assigned row per owned column (0 = free)
    float v_a = 0.f, v_b = 0.f;          // column potentials
    float u_reg = 0.f;                   // lane r in 1..20 holds u[r]

    // ---- greedy init: u[i] = min_j c[i][j]; assign i -> argmin col if free ----
    for (int i = 1; i <= T_; ++i) {
        float ca = ja_ok ? csh[(ja - 1) * CPAD + (i - 1)] : INFINITY;
        float cb = jb_ok ? csh[(jb - 1) * CPAD + (i - 1)] : INFINITY;
        float vmin = fminf(ca, cb);
        for (int off = 32; off > 0; off >>= 1)
            vmin = fminf(vmin, __shfl_xor(vmin, off));
        unsigned long long ba = __ballot(ca == vmin);
        int j1 = ba ? (__ffsll(ba) - 1) : (__ffsll(__ballot(cb == vmin)) - 1 + 64);
        if (lane == i) u_reg = vmin;
        int pj = __shfl((j1 < 64) ? p_a : p_b, j1 & 63);
        if (pj == 0) {
            if (j1 < 64) { if (lane == j1) p_a = i; }
            else         { if (lane == j1 - 64) p_b = i; }
        }
    }

    // ---- Dijkstra phases for unassigned rows ----
    for (int i = 1; i <= T_; ++i) {
        bool mine = (p_a == i) || (p_b == i);
        if (__ballot(mine)) continue;            // row already assigned (wave-uniform)

        float m_a = INFINITY, m_b = INFINITY;
        int   way_a = 0, way_b = 0;
        bool  us_a = false, us_b = false;
        bool  in_tree = (lane == i);
        int   j0 = 0, jf;

        while (true) {
            int i0 = (j0 == 0) ? i : __shfl((j0 < 64) ? p_a : p_b, j0 & 63);
            if (lane == i0) in_tree = true;
            float ui0 = __shfl(u_reg, i0);
            if (ja == j0) us_a = true;
            if (jb == j0) us_b = true;
            bool fa = ja_ok && !us_a;
            bool fb = jb_ok && !us_b;
            if (fa) {
                float cur = csh[(ja - 1) * CPAD + (i0 - 1)] - ui0 - v_a;
                if (cur < m_a) { m_a = cur; way_a = j0; }
            }
            if (fb) {
                float cur = csh[(jb - 1) * CPAD + (i0 - 1)] - ui0 - v_b;
                if (cur < m_b) { m_b = cur; way_b = j0; }
            }
            float ca = fa ? m_a : INFINITY;
            float cb = fb ? m_b : INFINITY;
            float vmin = fminf(ca, cb);
            for (int off = 32; off > 0; off >>= 1)
                vmin = fminf(vmin, __shfl_xor(vmin, off));
            unsigned long long ba = __ballot(ca == vmin);
            int j1 = ba ? (__ffsll(ba) - 1) : (__ffsll(__ballot(cb == vmin)) - 1 + 64);
            float delta = vmin;
            if (us_a) v_a -= delta; else m_a -= delta;
            if (us_b) v_b -= delta; else m_b -= delta;
            if (in_tree) u_reg += delta;
            j0 = j1;
            int pj0 = __shfl((j0 < 64) ? p_a : p_b, j0 & 63);
            if (pj0 == 0) { jf = j0; break; }
        }
        // augment along way[] (register walk, wave-uniform indices)
        int jj = jf;
        while (jj) {
            int wv = __shfl((jj < 64) ? way_a : way_b, jj & 63);              // way[jj]
            int pn = (wv == 0) ? i : __shfl((wv < 64) ? p_a : p_b, wv & 63);  // p[way[jj]]
            if (jj < 64) { if (lane == jj) p_a = pn; }
            else         { if (lane == jj - 64) p_b = pn; }
            jj = wv;
        }
    }

    // ---- output (ascending real-column order == ascending row order of the transposed LAP) ----
    if (ja_ok) psh[ja] = p_a;
    if (jb_ok) psh[jb] = p_b;
    if (lane == 0) psh[0] = 0;
    __syncthreads();
    if (lane == 0) {
        int* ob = out + b * 2 * T_;
        int k = 0;
        for (int j = 1; j <= NHUN; ++j) {
            if (psh[j] != 0) { ob[k] = j - 1; ob[T_ + k] = psh[j] - 1; ++k; }
        }
    }
}

extern "C" void kernel_launch(void* const* d_in, const int* in_sizes, int n_in,
                              void* d_out, int out_size, void* d_ws, size_t ws_size,
                              hipStream_t stream) {
    const float* mq     = (const float*)d_in[0];   // [2,100,256,256]
    const float* cl     = (const float*)d_in[1];   // [2,100,134]
    const float* ml     = (const float*)d_in[2];   // [2,20,512,512]
    const int*   labels = (const int*)d_in[3];     // [2,20]
    int* out = (int*)d_out;                        // [2,2,20] int32
    float* ws = (float*)d_ws;

    float* lab_ps = ws + LABPS_OFF;
    float* cc     = ws + CC_OFF;
    float* cost   = ws + COST_OFF;

    size_t need = (size_t)WS_END_F * 4;

    if (ws_size >= need) {
        unsigned short* labT = (unsigned short*)(ws + LABT_HI_F);
        float* part = ws + PART_OFF;
        float* Csum = ws + CSUM_OFF;
        hipLaunchKernelGGL(lab_prep_kernel,   dim3(B_, T_, 8), dim3(256), 0, stream,
                           ml, labT, lab_ps, 1);
        hipLaunchKernelGGL(focal_mfma_kernel, dim3(B_ * KSB * MT_), dim3(256), 0, stream,
                           mq, labT, part);
        hipLaunchKernelGGL(reduce_part_kernel, dim3(B_ * MT_, 33), dim3(256), 0, stream,
                           part, Csum);
        hipLaunchKernelGGL(compose_kernel,    dim3(B_ * MT_),  dim3(320), 0, stream,
                           Csum, cl, labels, lab_ps, cost);
    } else {
        hipLaunchKernelGGL(lab_prep_kernel,   dim3(B_, T_, 8), dim3(256), 0, stream,
                           ml, (unsigned short*)ws, lab_ps, 0);
        hipLaunchKernelGGL(class_cost_kernel, dim3(B_ * Q_),   dim3(64),  0, stream, cl, labels, cc);
        hipLaunchKernelGGL(mask_cost_mono_kernel, dim3(B_ * Q_), dim3(1024), 0, stream,
                           mq, ml, cc, lab_ps, cost);
    }
    hipLaunchKernelGGL(hungarian_kernel, dim3(B_), dim3(64), 0, stream, cost, out);
}

// Round 13
// 70.133 us; speedup vs baseline: 1.4132x; 1.0108x over previous
//
#include <hip/hip_runtime.h>
#include <hip/hip_bf16.h>
#include <math.h>

#define HW_   65536
#define B_    2
#define Q_    100
#define C_    134
#define T_    20
#define NHUN  100
#define MT_   7            // M-tiles of 16 queries (112 >= 100)
#define KSB   128          // K-split blocks per (b,mt)
#define BKCH  512          // k per block
#define PREC  1088         // part record stride (1024 frag + 16 F + 16 P + pad)
#define CPAD  21           // padded cost row stride (floats) in hungarian LDS

typedef __attribute__((ext_vector_type(8))) short bf16x8;
typedef __attribute__((ext_vector_type(4))) float f32x4;

// ws layout (float units)
#define LABPS_OFF  0                    // [2][20][8]
#define CC_OFF     512                  // [200][20] (fallback path only)
#define COST_OFF   4608                 // [200][20]
#define BASE_END   8704
#define LABT_HI_F  BASE_END                         // 2*20*65536 ushort = 1,310,720 floats
#define PART_OFF   (LABT_HI_F + 1310720)            // 1792 records * 1088 floats
#define CSUM_OFF   (PART_OFF + B_ * KSB * MT_ * PREC)   // 14*1056
#define WS_END_F   (CSUM_OFF + B_ * MT_ * 1056)

__device__ inline unsigned short f2bf(float f) {
    unsigned int u = __builtin_bit_cast(unsigned int, f);
    u += 0x7FFFu + ((u >> 16) & 1u);               // RNE
    return (unsigned short)(u >> 16);
}
__device__ inline float softplusf(float x) {
    float ax = fabsf(x);
    return fmaxf(x, 0.0f) + log1pf(expf(-ax));
}

// ---------------- K1: decimate labels -> bf16 rows [b][t][65536] + row-sum partials ----------------
__global__ void lab_prep_kernel(const float* __restrict__ ml, unsigned short* __restrict__ labT,
                                float* __restrict__ lab_ps, int writeT) {
    int b = blockIdx.x, t = blockIdx.y, ksl = blockIdx.z;
    int tid = threadIdx.x;
    const float* src = ml + (size_t)(b * T_ + t) * 262144;
    size_t dst = ((size_t)(b * T_ + t)) << 16;
    float acc = 0.f;
    for (int it = 0; it < 8; ++it) {
        int k = ksl * 8192 + it * 1024 + tid * 4;
        int r = k >> 8, c = k & 255;
        const float* s = src + r * 1024 + 2 * c;
        float4 u = *(const float4*)s;
        float4 w = *(const float4*)(s + 4);
        float v[4] = {u.x, u.z, w.x, w.z};
        unsigned short h[4];
#pragma unroll
        for (int e = 0; e < 4; ++e) { h[e] = f2bf(v[e]); acc += v[e]; }
        if (writeT) *(ushort4*)(labT + dst + k) = make_ushort4(h[0], h[1], h[2], h[3]);
    }
    for (int off = 32; off > 0; off >>= 1) acc += __shfl_down(acc, off);
    __shared__ float sb[4];
    int wid = tid >> 6, lane = tid & 63;
    if (lane == 0) sb[wid] = acc;
    __syncthreads();
    if (tid == 0) lab_ps[(b * T_ + t) * 8 + ksl] = sb[0] + sb[1] + sb[2] + sb[3];
}

// ---------------- class cost (fallback path only) ----------------
__global__ void class_cost_kernel(const float* __restrict__ cl, const int* __restrict__ labels,
                                  float* __restrict__ cc) {
    int bq  = blockIdx.x;
    int b   = bq / Q_;
    int tid = threadIdx.x;         // 64
    __shared__ float sl[C_];
    const float* src = cl + (size_t)bq * C_;
    for (int c = tid; c < C_; c += 64) sl[c] = src[c];
    __syncthreads();
    float mx = -INFINITY;
    for (int c = tid; c < C_; c += 64) mx = fmaxf(mx, sl[c]);
    for (int off = 32; off > 0; off >>= 1) mx = fmaxf(mx, __shfl_xor(mx, off));
    float se = 0.f;
    for (int c = tid; c < C_; c += 64) se += expf(sl[c] - mx);
    for (int off = 32; off > 0; off >>= 1) se += __shfl_xor(se, off);
    float inv = 1.0f / se;
    if (tid < T_) {
        int lbl = labels[b * T_ + tid];
        cc[bq * T_ + tid] = -expf(sl[lbl] - mx) * inv;
    }
}

// ---------------- K3: focal MFMA with full-block prefetch (ILP fix) ----------------
// blockIdx.x = (b*KSB + ks)*MT_ + mt ; 256 thr (4 waves, each 128 k).
// All 16 global loads for the block's 4 k-steps are issued up front (launch_bounds
// (256,4) -> <=128 VGPR so they stay in registers), then pointwise+MFMA on registers.
__global__ __launch_bounds__(256, 4) void focal_mfma_kernel(
        const float* __restrict__ mq, const unsigned short* __restrict__ labT,
        float* __restrict__ part) {
    int idx = blockIdx.x;
    int mt  = idx % MT_;
    int rem = idx / MT_;
    int ks  = rem % KSB;
    int b   = rem / KSB;
    int tid  = threadIdx.x;
    int wave = tid >> 6, lane = tid & 63;
    int lg = lane >> 4, lr = lane & 15;

    int q = mt * 16 + lr;
    bool qok = (q < Q_);
    const float* xrow = mq + ((size_t)(b * Q_ + (qok ? q : 0)) << 16);
    int koff = ks * BKCH + wave * 128 + lg * 8;

    const unsigned short* b1 = labT + (((size_t)(b * T_ + lr)) << 16);
    const unsigned short* b2 = labT + (((size_t)(b * T_ + 16 + (lr & 3))) << 16);
    bool n2row = (lr < 4);

    bf16x8 zer;
#pragma unroll
    for (int e = 0; e < 8; ++e) zer[e] = 0;

    // ---- prefetch phase: 16 independent loads in flight ----
    float4 a0[4], a1[4];
    bf16x8 bfrag1[4], bfrag2[4];
#pragma unroll
    for (int kk = 0; kk < 4; ++kk) {
        int kb = koff + kk * 32;
        a0[kk] = *(const float4*)(xrow + kb);
        a1[kk] = *(const float4*)(xrow + kb + 4);
        bfrag1[kk] = *(const bf16x8*)(b1 + kb);
        bfrag2[kk] = n2row ? *(const bf16x8*)(b2 + kb) : zer;
    }

    f32x4 accD0 = {0,0,0,0}, accD1 = {0,0,0,0};
    f32x4 accP0 = {0,0,0,0}, accP1 = {0,0,0,0};
    float F = 0.f, P = 0.f;

#pragma unroll
    for (int kk = 0; kk < 4; ++kk) {
        float xv[8] = {a0[kk].x, a0[kk].y, a0[kk].z, a0[kk].w,
                       a1[kk].x, a1[kk].y, a1[kk].z, a1[kk].w};
        bf16x8 dh, ph;
#pragma unroll
        for (int e = 0; e < 8; ++e) {
            float x  = xv[e];
            float ax = fabsf(x);
            float a  = __expf(-ax);
            float rr = 1.0f / (1.0f + a);
            float p  = (x >= 0.f) ? rr : a * rr;
            float om = (x >= 0.f) ? a * rr : rr;
            float l1 = __logf(1.0f + a);
            float spn = fmaxf(-x, 0.f) + l1;
            float spp = spn + x;
            float fp = 0.25f * om * om * spn;
            float fn = 0.75f * p * p * spp;
            F += fn; P += p;
            dh[e] = (short)f2bf(fp - fn);
            ph[e] = (short)f2bf(p);
        }
        accD0 = __builtin_amdgcn_mfma_f32_16x16x32_bf16(dh, bfrag1[kk], accD0, 0, 0, 0);
        accD1 = __builtin_amdgcn_mfma_f32_16x16x32_bf16(dh, bfrag2[kk], accD1, 0, 0, 0);
        accP0 = __builtin_amdgcn_mfma_f32_16x16x32_bf16(ph, bfrag1[kk], accP0, 0, 0, 0);
        accP1 = __builtin_amdgcn_mfma_f32_16x16x32_bf16(ph, bfrag2[kk], accP1, 0, 0, 0);
    }

    F += __shfl_down(F, 32); F += __shfl_down(F, 16);
    P += __shfl_down(P, 32); P += __shfl_down(P, 16);

    __shared__ float red[4][4][64][4];
    __shared__ float fpb[4][2][16];
#pragma unroll
    for (int r = 0; r < 4; ++r) {
        red[wave][0][lane][r] = accD0[r];
        red[wave][1][lane][r] = accD1[r];
        red[wave][2][lane][r] = accP0[r];
        red[wave][3][lane][r] = accP1[r];
    }
    if (lane < 16) { fpb[wave][0][lane] = F; fpb[wave][1][lane] = P; }
    __syncthreads();
    // vectorized epilogue: thread e4 covers frag elems e4*4..e4*4+3 (one float4 store)
    if (tid < 256) {
        int e4 = tid;                      // 256 float4 groups = 1024 floats
        int f  = e4 >> 6;                  // frag id 0..3
        int l2 = e4 & 63;                  // lane idx
        float4 s;
        s.x = red[0][f][l2][0] + red[1][f][l2][0] + red[2][f][l2][0] + red[3][f][l2][0];
        s.y = red[0][f][l2][1] + red[1][f][l2][1] + red[2][f][l2][1] + red[3][f][l2][1];
        s.z = red[0][f][l2][2] + red[1][f][l2][2] + red[2][f][l2][2] + red[3][f][l2][2];
        s.w = red[0][f][l2][3] + red[1][f][l2][3] + red[2][f][l2][3] + red[3][f][l2][3];
        *(float4*)(part + (size_t)idx * PREC + e4 * 4) = s;
    }
    if (tid < 16)
        part[(size_t)idx * PREC + 1024 + tid] =
            fpb[0][0][tid] + fpb[1][0][tid] + fpb[2][0][tid] + fpb[3][0][tid];
    else if (tid < 32) {
        int l = tid - 16;
        part[(size_t)idx * PREC + 1040 + l] =
            fpb[0][1][l] + fpb[1][1][l] + fpb[2][1][l] + fpb[3][1][l];
    }
}

// ---------------- K4a: parallel K-split reduction: part -> Csum[14][1056] ----------------
__global__ __launch_bounds__(256) void reduce_part_kernel(const float* __restrict__ part,
                                                          float* __restrict__ Csum) {
    int bm   = blockIdx.x;          // 0..13
    int mt   = bm % MT_;
    int b    = bm / MT_;
    int tid  = threadIdx.x;
    int epos = tid & 31;
    int grp  = tid >> 5;            // 0..7
    int e    = blockIdx.y * 32 + epos;   // 0..1055

    const float* base = part + (size_t)((b * KSB) * MT_ + mt) * PREC + e;
    float s = 0.f;
    for (int k = 0; k < 16; ++k) {
        s += base[(size_t)(grp * 16 + k) * MT_ * PREC];
    }
    __shared__ float red[8][33];
    red[grp][epos] = s;
    __syncthreads();
    if (tid < 32) {
        float tot = 0.f;
        for (int g = 0; g < 8; ++g) tot += red[g][tid];
        Csum[(size_t)bm * 1056 + e] = tot;
    }
}

// ---------------- K4b: finalize cost from Csum + fused class-softmax (R8-proven) ----------------
__global__ __launch_bounds__(320) void compose_kernel(
        const float* __restrict__ Csum, const float* __restrict__ cl,
        const int* __restrict__ labels, const float* __restrict__ lab_ps,
        float* __restrict__ cost) {
    int bm = blockIdx.x;
    int mt = bm % MT_;
    int b  = bm / MT_;
    int tid = threadIdx.x;     // 320
    int q0 = mt * 16;

    __shared__ float sl[16][136];
    __shared__ float mx[16], se[16];
    __shared__ int   lbl[T_];
    for (int e = tid; e < 16 * C_; e += 320) {
        int qm = e / C_, c = e % C_;
        int q = q0 + qm;
        sl[qm][c] = (q < Q_) ? cl[(size_t)(b * Q_ + q) * C_ + c] : 0.f;
    }
    if (tid < T_) lbl[tid] = labels[b * T_ + tid];
    __syncthreads();
    if (tid < 16) {
        float m = -INFINITY;
        for (int c = 0; c < C_; ++c) m = fmaxf(m, sl[tid][c]);
        float s = 0.f;
        for (int c = 0; c < C_; ++c) s += expf(sl[tid][c] - m);
        mx[tid] = m; se[tid] = s;
    }
    __syncthreads();

    int qm = tid / T_, t = tid % T_;
    int q = q0 + qm;
    if (qm < 16 && q < Q_) {
        const float* C = Csum + (size_t)bm * 1056;
        int nt   = t >> 4;
        int lane = ((qm >> 2) << 4) | (t & 15);
        int reg  = qm & 3;
        float Sd = C[(0 + nt) * 256 + lane * 4 + reg];
        float Sp = C[(2 + nt) * 256 + lane * 4 + reg];
        float F  = C[1024 + qm];
        float P  = C[1040 + qm];
        float L = 0.f;
        for (int s8 = 0; s8 < 8; ++s8) L += lab_ps[(b * T_ + t) * 8 + s8];
        float ccv = -expf(sl[qm][lbl[t]] - mx[qm]) / se[qm];
        float cm = (Sd + F) * (1.0f / (float)HW_);
        float cd = 1.0f - (2.0f * Sp + 1.0f) / (P + L + 1.0f);
        cost[(size_t)(b * Q_ + q) * T_ + t] = cm + cd + ccv;
    }
}

// ---------------- fallback: monolithic (round-2 proven) ----------------
__global__ __launch_bounds__(1024) void mask_cost_mono_kernel(
        const float* __restrict__ mq, const float* __restrict__ ml,
        const float* __restrict__ cc, const float* __restrict__ lab_ps,
        float* __restrict__ cost) {
    int bq  = blockIdx.x;
    int b   = bq / Q_;
    int tid = threadIdx.x;
    const float* xb  = mq + (size_t)bq * HW_;
    const float* mlb = ml + (size_t)b * T_ * 262144;
    float s1[T_], s2[T_];
#pragma unroll
    for (int t = 0; t < T_; ++t) { s1[t] = 0.f; s2[t] = 0.f; }
    float F = 0.f, P = 0.f;
    for (int k = tid; k < HW_; k += 1024) {
        int i = k >> 8, j = k & 255;
        float x = xb[k];
        float p = 1.0f / (1.0f + expf(-x));
        float spn = softplusf(-x);
        float spp = softplusf(x);
        float om = 1.0f - p;
        float fp = 0.25f * om * om * spn;
        float fn = 0.75f * p * p * spp;
        F += fn; P += p;
        float diff = fp - fn;
        int off0 = i * 1024 + 2 * j;
#pragma unroll
        for (int t = 0; t < T_; ++t) {
            float lab = mlb[t * 262144 + off0];
            s1[t] = fmaf(diff, lab, s1[t]);
            s2[t] = fmaf(p,    lab, s2[t]);
        }
    }
    __shared__ float sbuf[16][42];
    int wid = tid >> 6, lane = tid & 63;
#pragma unroll
    for (int t = 0; t < T_; ++t) {
        for (int off = 32; off > 0; off >>= 1) {
            s1[t] += __shfl_down(s1[t], off);
            s2[t] += __shfl_down(s2[t], off);
        }
    }
    for (int off = 32; off > 0; off >>= 1) { F += __shfl_down(F, off); P += __shfl_down(P, off); }
    if (lane == 0) {
#pragma unroll
        for (int t = 0; t < T_; ++t) { sbuf[wid][t] = s1[t]; sbuf[wid][T_ + t] = s2[t]; }
        sbuf[wid][40] = F; sbuf[wid][41] = P;
    }
    __syncthreads();
    if (tid < T_) {
        float S1 = 0.f, S2 = 0.f, Fs = 0.f, Ps = 0.f;
        for (int w = 0; w < 16; ++w) {
            S1 += sbuf[w][tid]; S2 += sbuf[w][T_ + tid];
            Fs += sbuf[w][40];  Ps += sbuf[w][41];
        }
        float L = 0.f;
        for (int sl = 0; sl < 8; ++sl) L += lab_ps[(b * T_ + tid) * 8 + sl];
        float cm = (S1 + Fs) * (1.0f / (float)HW_);
        float cd = 1.0f - (2.0f * S2 + 1.0f) / (Ps + L + 1.0f);
        cost[bq * T_ + tid] = cm + cd + cc[bq * T_ + tid];
    }
}

// ---------------- K5: register-resident JV Hungarian with greedy row-reduction init (R12-proven) ----------------
__global__ __launch_bounds__(64) void hungarian_kernel(const float* __restrict__ cost,
                                                       int* __restrict__ out) {
    int b    = blockIdx.x;
    int lane = threadIdx.x;

    __shared__ float csh[Q_ * CPAD];
    __shared__ int   psh[NHUN + 1];

    for (int j = lane; j < Q_; j += 64) {
#pragma unroll
        for (int t = 0; t < T_; ++t)
            csh[j * CPAD + t] = cost[b * Q_ * T_ + j * T_ + t];
    }
    __syncthreads();

    const int ja = lane;
    const int jb = lane + 64;
    const bool ja_ok = (ja >= 1);
    const bool jb_ok = (jb <= NHUN);

    int   p_a = 0, p_b = 0;
    float v_a = 0.f, v_b = 0.f;
    float u_reg = 0.f;

    for (int i = 1; i <= T_; ++i) {
        float ca = ja_ok ? csh[(ja - 1) * CPAD + (i - 1)] : INFINITY;
        float cb = jb_ok ? csh[(jb - 1) * CPAD + (i - 1)] : INFINITY;
        float vmin = fminf(ca, cb);
        for (int off = 32; off > 0; off >>= 1)
            vmin = fminf(vmin, __shfl_xor(vmin, off));
        unsigned long long ba = __ballot(ca == vmin);
        int j1 = ba ? (__ffsll(ba) - 1) : (__ffsll(__ballot(cb == vmin)) - 1 + 64);
        if (lane == i) u_reg = vmin;
        int pj = __shfl((j1 < 64) ? p_a : p_b, j1 & 63);
        if (pj == 0) {
            if (j1 < 64) { if (lane == j1) p_a = i; }
            else         { if (lane == j1 - 64) p_b = i; }
        }
    }

    for (int i = 1; i <= T_; ++i) {
        bool mine = (p_a == i) || (p_b == i);
        if (__ballot(mine)) continue;

        float m_a = INFINITY, m_b = INFINITY;
        int   way_a = 0, way_b = 0;
        bool  us_a = false, us_b = false;
        bool  in_tree = (lane == i);
        int   j0 = 0, jf;

        while (true) {
            int i0 = (j0 == 0) ? i : __shfl((j0 < 64) ? p_a : p_b, j0 & 63);
            if (lane == i0) in_tree = true;
            float ui0 = __shfl(u_reg, i0);
            if (ja == j0) us_a = true;
            if (jb == j0) us_b = true;
            bool fa = ja_ok && !us_a;
            bool fb = jb_ok && !us_b;
            if (fa) {
                float cur = csh[(ja - 1) * CPAD + (i0 - 1)] - ui0 - v_a;
                if (cur < m_a) { m_a = cur; way_a = j0; }
            }
            if (fb) {
                float cur = csh[(jb - 1) * CPAD + (i0 - 1)] - ui0 - v_b;
                if (cur < m_b) { m_b = cur; way_b = j0; }
            }
            float ca = fa ? m_a : INFINITY;
            float cb = fb ? m_b : INFINITY;
            float vmin = fminf(ca, cb);
            for (int off = 32; off > 0; off >>= 1)
                vmin = fminf(vmin, __shfl_xor(vmin, off));
            unsigned long long ba = __ballot(ca == vmin);
            int j1 = ba ? (__ffsll(ba) - 1) : (__ffsll(__ballot(cb == vmin)) - 1 + 64);
            float delta = vmin;
            if (us_a) v_a -= delta; else m_a -= delta;
            if (us_b) v_b -= delta; else m_b -= delta;
            if (in_tree) u_reg += delta;
            j0 = j1;
            int pj0 = __shfl((j0 < 64) ? p_a : p_b, j0 & 63);
            if (pj0 == 0) { jf = j0; break; }
        }
        int jj = jf;
        while (jj) {
            int wv = __shfl((jj < 64) ? way_a : way_b, jj & 63);
            int pn = (wv == 0) ? i : __shfl((wv < 64) ? p_a : p_b, wv & 63);
            if (jj < 64) { if (lane == jj) p_a = pn; }
            else         { if (lane == jj - 64) p_b = pn; }
            jj = wv;
        }
    }

    if (ja_ok) psh[ja] = p_a;
    if (jb_ok) psh[jb] = p_b;
    if (lane == 0) psh[0] = 0;
    __syncthreads();
    if (lane == 0) {
        int* ob = out + b * 2 * T_;
        int k = 0;
        for (int j = 1; j <= NHUN; ++j) {
            if (psh[j] != 0) { ob[k] = j - 1; ob[T_ + k] = psh[j] - 1; ++k; }
        }
    }
}

extern "C" void kernel_launch(void* const* d_in, const int* in_sizes, int n_in,
                              void* d_out, int out_size, void* d_ws, size_t ws_size,
                              hipStream_t stream) {
    const float* mq     = (const float*)d_in[0];   // [2,100,256,256]
    const float* cl     = (const float*)d_in[1];   // [2,100,134]
    const float* ml     = (const float*)d_in[2];   // [2,20,512,512]
    const int*   labels = (const int*)d_in[3];     // [2,20]
    int* out = (int*)d_out;                        // [2,2,20] int32
    float* ws = (float*)d_ws;

    float* lab_ps = ws + LABPS_OFF;
    float* cc     = ws + CC_OFF;
    float* cost   = ws + COST_OFF;

    size_t need = (size_t)WS_END_F * 4;

    if (ws_size >= need) {
        unsigned short* labT = (unsigned short*)(ws + LABT_HI_F);
        float* part = ws + PART_OFF;
        float* Csum = ws + CSUM_OFF;
        hipLaunchKernelGGL(lab_prep_kernel,   dim3(B_, T_, 8), dim3(256), 0, stream,
                           ml, labT, lab_ps, 1);
        hipLaunchKernelGGL(focal_mfma_kernel, dim3(B_ * KSB * MT_), dim3(256), 0, stream,
                           mq, labT, part);
        hipLaunchKernelGGL(reduce_part_kernel, dim3(B_ * MT_, 33), dim3(256), 0, stream,
                           part, Csum);
        hipLaunchKernelGGL(compose_kernel,    dim3(B_ * MT_),  dim3(320), 0, stream,
                           Csum, cl, labels, lab_ps, cost);
    } else {
        hipLaunchKernelGGL(lab_prep_kernel,   dim3(B_, T_, 8), dim3(256), 0, stream,
                           ml, (unsigned short*)ws, lab_ps, 0);
        hipLaunchKernelGGL(class_cost_kernel, dim3(B_ * Q_),   dim3(64),  0, stream, cl, labels, cc);
        hipLaunchKernelGGL(mask_cost_mono_kernel, dim3(B_ * Q_), dim3(1024), 0, stream,
                           mq, ml, cc, lab_ps, cost);
    }
    hipLaunchKernelGGL(hungarian_kernel, dim3(B_), dim3(64), 0, stream, cost, out);
}